// Round 7
// baseline (500.199 us; speedup 1.0000x reference)
//
#include <hip/hip_runtime.h>
#include <hip/hip_bf16.h>

typedef __attribute__((ext_vector_type(8))) short bf16x8;
typedef __attribute__((ext_vector_type(4))) float f32x4;

#define DEVFN static __device__ __forceinline__

constexpr int kSQ = 2048, kSKV = 2048, kD = 1024, kH = 16;
constexpr int kM = 4 * kSQ;   // 8192 rows (B*SQ)

DEVFN unsigned short f2bf(float f) {
  union { float f; unsigned u; } v; v.f = f;
  unsigned r = v.u + 0x7FFFu + ((v.u >> 16) & 1u);
  return (unsigned short)(r >> 16);
}
DEVFN float bf2f(unsigned short h) {
  union { unsigned u; float f; } v; v.u = ((unsigned)h) << 16; return v.f;
}
DEVFN unsigned cvtpk(float lo, float hi) {
  unsigned r;
  asm("v_cvt_pk_bf16_f32 %0, %1, %2" : "=v"(r) : "v"(lo), "v"(hi));
  return r;
}
DEVFN float vexp2(float x) {
  float r;
  asm("v_exp_f32 %0, %1" : "=v"(r) : "v"(x));
  return r;
}

DEVFN void gload16(const void* g, void* l) {
  __builtin_amdgcn_global_load_lds(
      (const __attribute__((address_space(1))) unsigned int*)g,
      (__attribute__((address_space(3))) unsigned int*)l, 16, 0, 0);
}

// ---------------------------------------------------------------------------
// Swizzled-tiled operand layouts (producer-side swizzle -> GEMM stages are
// perfectly LINEAR global_load_lds, and ds_read_b128 is 2-way-bank-free):
//   A (8192x1024):  [p<32][kt<16][r<256][u<8][8]   u = (c>>3) ^ (r&7), c=col
//   B (Nx1024, N-major): [np<N/128][kt<16][r<128][u<8][8]  same rule
// ---------------------------------------------------------------------------

// Kernel 1 (merged): blocks [0, 2*kM): activation fp32->bf16 (swizzled-tiled)
// + LoRA-down dots. blocks [2*kM, 2*kM+1024): weight convert+transpose into
// swizzled-tiled B layout.
__global__ __launch_bounds__(256) void k_prep_wt(
    const float* __restrict__ hs, const float* __restrict__ enc,
    const float* __restrict__ qdn, const float* __restrict__ kdn,
    const float* __restrict__ vdn,
    const float* __restrict__ Wq, const float* __restrict__ Wk,
    const float* __restrict__ Wv, const float* __restrict__ Wo,
    unsigned short* __restrict__ hsb, unsigned short* __restrict__ encb,
    float* __restrict__ tq, float* __restrict__ tkv,
    unsigned short* __restrict__ Wqt, unsigned short* __restrict__ Wkvt,
    unsigned short* __restrict__ Wot) {
  __shared__ float red[4][8];
  __shared__ unsigned short tile[64][65];
  const int bid = blockIdx.x;
  const int tid = threadIdx.x;

  if (bid < 2 * kM) {
    const bool isH = bid < kM;
    const int rr = isH ? bid : bid - kM;
    const float* srcRow = (isH ? hs : enc) + (size_t)rr * kD;
    unsigned short* dstB = isH ? hsb : encb;

    float4 x = reinterpret_cast<const float4*>(srcRow)[tid];
    short4 o;
    o.x = (short)f2bf(x.x); o.y = (short)f2bf(x.y);
    o.z = (short)f2bf(x.z); o.w = (short)f2bf(x.w);
    // swizzled-tiled write: c = tid*4
    {
      const int p = rr >> 8, r = rr & 255;
      const int kt = tid >> 4, us = (tid >> 1) & 7, e = (tid & 1) * 4;
      const int u = us ^ (r & 7);
      *reinterpret_cast<short4*>(
          &dstB[(((size_t)(p * 16 + kt)) * 256 + r) * 64 + u * 8 + e]) = o;
    }

    float xs[4] = {x.x, x.y, x.z, x.w};
    float a[4] = {0.f, 0.f, 0.f, 0.f};
    float bacc[4] = {0.f, 0.f, 0.f, 0.f};
    const float* dnA = isH ? qdn : kdn;
    const int base = tid * 4;
#pragma unroll
    for (int e = 0; e < 4; ++e) {
      const float* dr = dnA + (size_t)(base + e) * 4;
      a[0] += xs[e] * dr[0]; a[1] += xs[e] * dr[1];
      a[2] += xs[e] * dr[2]; a[3] += xs[e] * dr[3];
    }
    if (!isH) {
#pragma unroll
      for (int e = 0; e < 4; ++e) {
        const float* dr = vdn + (size_t)(base + e) * 4;
        bacc[0] += xs[e] * dr[0]; bacc[1] += xs[e] * dr[1];
        bacc[2] += xs[e] * dr[2]; bacc[3] += xs[e] * dr[3];
      }
    }
    const int l = tid & 63, w = tid >> 6;
    float vals[8] = {a[0], a[1], a[2], a[3], bacc[0], bacc[1], bacc[2], bacc[3]};
#pragma unroll
    for (int k2 = 0; k2 < 8; ++k2) {
      float v = vals[k2];
#pragma unroll
      for (int m = 1; m < 64; m <<= 1) v += __shfl_xor(v, m);
      if (l == 0) red[w][k2] = v;
    }
    __syncthreads();
    if (tid < 8) {
      float s = red[0][tid] + red[1][tid] + red[2][tid] + red[3][tid];
      if (isH) {
        if (tid < 4) tq[(size_t)rr * 4 + tid] = s;
      } else {
        tkv[(size_t)rr * 8 + tid] = s;   // 0..3 = k-down, 4..7 = v-down
      }
    }
  } else {
    const int t2 = bid - 2 * kM;
    const int wid = t2 >> 8, tt = t2 & 255;
    const float* W = (wid == 0) ? Wq : (wid == 1) ? Wk : (wid == 2) ? Wv : Wo;
    unsigned short* Wt = (wid == 0) ? Wqt : (wid <= 2) ? Wkvt : Wot;
    const int npOff = (wid == 2) ? 8 : 0;   // V weights occupy panels 8..15
    const int tk0 = (tt & 15) * 64;
    const int tn0 = (tt >> 4) * 64;
    for (int i = tid; i < 4096; i += 256) {
      int r = i >> 6, c = i & 63;
      tile[r][c] = f2bf(W[(size_t)(tk0 + r) * 1024 + tn0 + c]);
    }
    __syncthreads();
    const int kt = tk0 >> 6;
    for (int i = tid; i < 4096; i += 256) {
      int r2 = i >> 6, c2 = i & 63;       // r2 = n-offset, c2 = k-offset
      const int n = tn0 + r2;
      const int np = (n >> 7) + npOff, rB = n & 127;
      const int u = (c2 >> 3) ^ (rB & 7), e = c2 & 7;
      Wt[(((size_t)np * 16 + kt) * 128 + rB) * 64 + u * 8 + e] = tile[c2][r2];
    }
  }
}

// ---------------------------------------------------------------------------
// m201-style 8-phase 256x256 GEMM core. BK=64, 16 K-tiles, 8 waves (2M x 4N),
// LDS 2dbuf x 2half x 16KB per matrix = 128KB. Per K-tile: 4 phases of
// {ds_read subtile || stage -> barrier -> lgkmcnt(0) -> 16 MFMA -> barrier}.
// Tile kt+1 staged (8 linear gloads) at phase 1 of tile kt's group into the
// buffer freed at the end of group kt-1. vmcnt(0) only at group boundaries.

#define GSTG(kt, d) do {                                                      \
    _Pragma("unroll") for (int h2 = 0; h2 < 2; ++h2)                          \
      _Pragma("unroll") for (int j = 0; j < 2; ++j) {                         \
        gload16(Abase + ((size_t)(p16 + (kt)) * 16384) + h2 * 8192            \
                    + (j * 8 + w) * 512 + l * 8,                              \
                &lA[d][h2][(j * 8 + w) * 512]);                               \
        gload16(Bbase + ((size_t)((np0 + h2) * 16 + (kt)) * 8192)             \
                    + (j * 8 + w) * 512 + l * 8,                              \
                &lB[d][h2][(j * 8 + w) * 512]);                               \
      } } while (0)

#define LDA4(hp, kk, mh) do { _Pragma("unroll") for (int m_ = 0; m_ < 4; ++m_)\
    a_[m_] = *(const bf16x8*)&(hp)[(((mh) * 4 + m_) * 16 + lr) * 64           \
               + ((((kk) * 4 + lk) ^ swz)) * 8]; } while (0)
#define LDB4(hp, kk) do { _Pragma("unroll") for (int n_ = 0; n_ < 4; ++n_)    \
    b_[n_] = *(const bf16x8*)&(hp)[(rb0 + n_ * 16 + lr) * 64                  \
               + ((((kk) * 4 + lk) ^ swz)) * 8]; } while (0)
#define MF16(mb) do { _Pragma("unroll") for (int m_ = 0; m_ < 4; ++m_)        \
    _Pragma("unroll") for (int n_ = 0; n_ < 4; ++n_)                          \
      acc[(mb) + m_][n_] = __builtin_amdgcn_mfma_f32_16x16x32_bf16(           \
          a_[m_], b_[n_], acc[(mb) + m_][n_], 0, 0, 0); } while (0)

#define GEMM8_LOOP()                                                          \
  bf16x8 a_[4], b_[4];                                                        \
  GSTG(0, 0);                                                                 \
  asm volatile("s_waitcnt vmcnt(0)" ::: "memory");                            \
  __builtin_amdgcn_s_barrier();                                               \
  for (int kt = 0; kt < 16; ++kt) {                                           \
    const int c = kt & 1;                                                     \
    const unsigned short* hA = &lA[c][wmh][0];                                \
    const unsigned short* hB = &lB[c][hb][0];                                 \
    /* phase 1 */                                                             \
    LDA4(hA, 0, 0);  LDB4(hB, 0);                                             \
    if (kt < 15) GSTG(kt + 1, c ^ 1);                                         \
    __builtin_amdgcn_s_barrier();                                             \
    asm volatile("s_waitcnt lgkmcnt(0)" ::: "memory");                        \
    __builtin_amdgcn_s_setprio(1);  MF16(0);                                  \
    __builtin_amdgcn_s_setprio(0);  __builtin_amdgcn_s_barrier();             \
    /* phase 2 */                                                             \
    LDA4(hA, 0, 1);                                                           \
    __builtin_amdgcn_s_barrier();                                             \
    asm volatile("s_waitcnt lgkmcnt(0)" ::: "memory");                        \
    __builtin_amdgcn_s_setprio(1);  MF16(4);                                  \
    __builtin_amdgcn_s_setprio(0);  __builtin_amdgcn_s_barrier();             \
    /* phase 3 */                                                             \
    LDA4(hA, 1, 0);  LDB4(hB, 1);                                             \
    __builtin_amdgcn_s_barrier();                                             \
    asm volatile("s_waitcnt lgkmcnt(0)" ::: "memory");                        \
    __builtin_amdgcn_s_setprio(1);  MF16(0);                                  \
    __builtin_amdgcn_s_setprio(0);  __builtin_amdgcn_s_barrier();             \
    /* phase 4 */                                                             \
    LDA4(hA, 1, 1);                                                           \
    __builtin_amdgcn_s_barrier();                                             \
    asm volatile("s_waitcnt lgkmcnt(0)" ::: "memory");                        \
    __builtin_amdgcn_s_setprio(1);  MF16(4);                                  \
    __builtin_amdgcn_s_setprio(0);                                            \
    asm volatile("s_waitcnt vmcnt(0)" ::: "memory");                          \
    __builtin_amdgcn_s_barrier();                                             \
  }

// Kernel 2: QKV projection. blocks [0,128): Q (N=1024); [128,384): K|V (N=2048).
__global__ __launch_bounds__(512, 2) void k_gemm_qkv(
    const unsigned short* __restrict__ hsb, const unsigned short* __restrict__ encb,
    const unsigned short* __restrict__ Wqt, const unsigned short* __restrict__ Wkvt,
    const float* __restrict__ tq, const float* __restrict__ tkv,
    const float* __restrict__ q_up, const float* __restrict__ k_up,
    const float* __restrict__ v_up,
    unsigned short* __restrict__ Qhp, unsigned short* __restrict__ Khp,
    unsigned short* __restrict__ Vhp) {
  __shared__ unsigned short lA[2][2][8192];
  __shared__ unsigned short lB[2][2][8192];
  const int tid = threadIdx.x;
  const int l = tid & 63, w = tid >> 6;
  const int bid = blockIdx.x;

  const unsigned short *Abase, *Bbase;
  const float *tmat, *up;
  unsigned short* dst;
  int p, nb, nOut0, tstr;
  if (bid < 128) {
    const int rid = (bid & 7) * 16 + (bid >> 3);
    nb = rid & 3; p = rid >> 2;
    Abase = hsb; Bbase = Wqt; tmat = tq; tstr = 4; up = q_up; dst = Qhp;
    nOut0 = nb * 256;
  } else {
    const int b2 = bid - 128;
    const int rid = (b2 & 7) * 32 + (b2 >> 3);
    nb = rid & 7; p = rid >> 3;
    Abase = encb; Bbase = Wkvt; tstr = 8;
    if (nb < 4) { tmat = tkv;     up = k_up; dst = Khp; nOut0 = nb * 256; }
    else        { tmat = tkv + 4; up = v_up; dst = Vhp; nOut0 = nb * 256 - 1024; }
  }
  const int p16 = p * 16, np0 = nb * 2;
  const int wmh = w >> 2, wc4 = w & 3;
  const int hb = wc4 >> 1, rb0 = (wc4 & 1) * 64;
  const int lr = l & 15, lk = l >> 4;
  const int swz = lr & 7;

  f32x4 acc[8][4];
  const f32x4 zero = {0.f, 0.f, 0.f, 0.f};
#pragma unroll
  for (int m = 0; m < 8; ++m)
#pragma unroll
    for (int n = 0; n < 4; ++n) acc[m][n] = zero;

  GEMM8_LOOP()

  const int m0 = p * 256, wr = wmh * 128, wc = wc4 * 64;
#pragma unroll
  for (int n = 0; n < 4; ++n) {
    const int gcol = nOut0 + wc + n * 16 + lr;
    const float u0 = up[gcol], u1 = up[1024 + gcol];
    const float u2 = up[2048 + gcol], u3 = up[3072 + gcol];
    const int h = gcol >> 6, d = gcol & 63;
#pragma unroll
    for (int m = 0; m < 8; ++m) {
#pragma unroll
      for (int r = 0; r < 4; ++r) {
        const int grow = m0 + wr + m * 16 + lk * 4 + r;
        const float4 tt = *reinterpret_cast<const float4*>(tmat + (size_t)grow * tstr);
        const float val = acc[m][n][r] + tt.x * u0 + tt.y * u1 + tt.z * u2 + tt.w * u3;
        const int b = grow >> 11, s = grow & 2047;
        dst[(((size_t)(b * kH + h)) * 2048 + s) * 64 + d] = f2bf(val);
      }
    }
  }
}

// Kernel 3: out = Ob @ Wot^T + bias + t_o @ o_up (f32). 128 blocks, 256^2.
__global__ __launch_bounds__(512, 2) void k_gemm_out(
    const unsigned short* __restrict__ Ob, const unsigned short* __restrict__ Wot,
    const float* __restrict__ tmat, const float* __restrict__ up,
    const float* __restrict__ bias, float* __restrict__ outp) {
  __shared__ unsigned short lA[2][2][8192];
  __shared__ unsigned short lB[2][2][8192];
  const int tid = threadIdx.x;
  const int l = tid & 63, w = tid >> 6;
  const int rid = (blockIdx.x & 7) * 16 + (blockIdx.x >> 3);
  const int nb = rid & 3, p = rid >> 2;
  const unsigned short* Abase = Ob;
  const unsigned short* Bbase = Wot;
  const int p16 = p * 16, np0 = nb * 2;
  const int wmh = w >> 2, wc4 = w & 3;
  const int hb = wc4 >> 1, rb0 = (wc4 & 1) * 64;
  const int lr = l & 15, lk = l >> 4;
  const int swz = lr & 7;

  f32x4 acc[8][4];
  const f32x4 zero = {0.f, 0.f, 0.f, 0.f};
#pragma unroll
  for (int m = 0; m < 8; ++m)
#pragma unroll
    for (int n = 0; n < 4; ++n) acc[m][n] = zero;

  GEMM8_LOOP()

  const int m0 = p * 256, wr = wmh * 128, wc = wc4 * 64;
#pragma unroll
  for (int n = 0; n < 4; ++n) {
    const int gcol = nb * 256 + wc + n * 16 + lr;
    const float u0 = up[gcol], u1 = up[1024 + gcol];
    const float u2 = up[2048 + gcol], u3 = up[3072 + gcol];
    const float bz = bias[gcol];
#pragma unroll
    for (int m = 0; m < 8; ++m) {
#pragma unroll
      for (int r = 0; r < 4; ++r) {
        const int grow = m0 + wr + m * 16 + lk * 4 + r;
        const float4 tt = *reinterpret_cast<const float4*>(tmat + (size_t)grow * 4);
        outp[(size_t)grow * 1024 + gcol] =
            acc[m][n][r] + tt.x * u0 + tt.y * u1 + tt.z * u2 + tt.w * u3 + bz;
      }
    }
  }
}

// ---------------------------------------------------------------------------
// Kernel 4: V head-layout transpose: (bh, s, d) -> (bh, d, s)
__global__ __launch_bounds__(256) void k_vt(const unsigned short* __restrict__ Vh,
                                            unsigned short* __restrict__ Vt) {
  __shared__ unsigned short tile[64][65];
  const int bh = blockIdx.y;
  const int s0 = blockIdx.x * 64;
  const unsigned short* src = Vh + ((size_t)bh * kSKV + s0) * 64;
  for (int i = threadIdx.x; i < 4096; i += 256) {
    int r = i >> 6, c = i & 63;
    tile[r][c] = src[(size_t)r * 64 + c];
  }
  __syncthreads();
  unsigned short* dst = Vt + (size_t)bh * 64 * kSKV + s0;
  for (int i = threadIdx.x; i < 4096; i += 256) {
    int r = i >> 6, c = i & 63;
    dst[(size_t)r * kSKV + c] = tile[c][r];
  }
}

// ---------------------------------------------------------------------------
// Kernel 5: flash attention (round-3 structure, best measured). Output written
// in swizzled-tiled A layout for the out-GEMM.
__global__ __launch_bounds__(256) void k_attn(
    const unsigned short* __restrict__ Qh, const unsigned short* __restrict__ Kh,
    const unsigned short* __restrict__ Vt, unsigned short* __restrict__ Obf) {
  __shared__ unsigned short lK[2][4096];
  __shared__ unsigned short lV[2][4096];
  __shared__ __align__(16) unsigned short lP[4][1024];

  const int bid = blockIdx.x + 16 * blockIdx.y;              // 1024 blocks
  const int rid = (bid & 7) * 128 + (bid >> 3);
  const int q0 = (rid & 15) * 128;
  const int bh = rid >> 4;

  const int tid = threadIdx.x;
  const int l = tid & 63, w = tid >> 6;
  const int lr = l & 15, lk = l >> 4;
  const int m7 = lr & 7;
  const int lkh = lk >> 1, lkb = lk & 1;

  const unsigned short* Qb = Qh + (size_t)bh * kSQ * 64;
  const unsigned short* Kb = Kh + (size_t)bh * kSKV * 64;
  const unsigned short* Vb = Vt + (size_t)bh * 64 * kSKV;

  const float QS = 0.125f * 1.4426950408889634f;
  bf16x8 qf[2][2];
#pragma unroll
  for (int m = 0; m < 2; ++m)
#pragma unroll
    for (int kk = 0; kk < 2; ++kk) {
      bf16x8 v = *(const bf16x8*)
          &Qb[(size_t)(q0 + w * 32 + m * 16 + lr) * 64 + kk * 32 + lk * 8];
#pragma unroll
      for (int j = 0; j < 8; ++j) {
        unsigned short u = (unsigned short)v[j];
        v[j] = (short)f2bf(bf2f(u) * QS);
      }
      qf[m][kk] = v;
    }

  f32x4 oacc[2][4];
  const f32x4 zero = {0.f, 0.f, 0.f, 0.f};
#pragma unroll
  for (int m = 0; m < 2; ++m)
#pragma unroll
    for (int n = 0; n < 4; ++n) oacc[m][n] = zero;
  float lrow[2] = {0.f, 0.f};

  const int sr8 = l >> 3;
  const int su = (l & 7) ^ sr8;
  unsigned short* lPw = lP[w];

#define ASTAGE(dbuf, tile) do { \
    _Pragma("unroll") for (int cc = 0; cc < 2; ++cc) { \
      const int c = 2 * w + cc; const int row = c * 8 + sr8; \
      gload16(Kb + (size_t)((tile) * 64 + row) * 64 + su * 8, &lK[dbuf][c * 512]); \
      gload16(Vb + (size_t)row * kSKV + (tile) * 64 + su * 8, &lV[dbuf][c * 512]); \
    } } while (0)

  ASTAGE(0, 0);
  __syncthreads();

#pragma unroll 2
  for (int kt = 0; kt < 32; ++kt) {
    const int cur = kt & 1;
    if (kt < 31) ASTAGE(cur ^ 1, kt + 1);
    const unsigned short* bufK = lK[cur];
    const unsigned short* bufV = lV[cur];

    bf16x8 kf[4][2];
#pragma unroll
    for (int n = 0; n < 4; ++n)
#pragma unroll
      for (int kk = 0; kk < 2; ++kk) {
        const int ub = (kk * 4 + lk) ^ m7;
        kf[n][kk] = *(const bf16x8*)&bufK[(n * 16 + lr) * 64 + ub * 8];
      }

    f32x4 s0[4];
#pragma unroll
    for (int n = 0; n < 4; ++n) s0[n] = zero;
    __builtin_amdgcn_s_setprio(1);
#pragma unroll
    for (int kk = 0; kk < 2; ++kk)
#pragma unroll
      for (int n = 0; n < 4; ++n)
        s0[n] = __builtin_amdgcn_mfma_f32_16x16x32_bf16(kf[n][kk], qf[0][kk],
                                                        s0[n], 0, 0, 0);
    __builtin_amdgcn_s_setprio(0);
    float ls0 = 0.f;
#pragma unroll
    for (int n = 0; n < 4; ++n) {
      const float p0 = vexp2(s0[n][0]);
      const float p1 = vexp2(s0[n][1]);
      const float p2 = vexp2(s0[n][2]);
      const float p3 = vexp2(s0[n][3]);
      ls0 += (p0 + p1) + (p2 + p3);
      uint2 pv; pv.x = cvtpk(p0, p1); pv.y = cvtpk(p2, p3);
      *(uint2*)&lPw[lr * 64 + (((2 * n + lkh) ^ m7) << 3) + lkb * 4] = pv;
    }
    lrow[0] += ls0;

    f32x4 s1[4];
#pragma unroll
    for (int n = 0; n < 4; ++n) s1[n] = zero;
    __builtin_amdgcn_s_setprio(1);
#pragma unroll
    for (int kk = 0; kk < 2; ++kk)
#pragma unroll
      for (int n = 0; n < 4; ++n)
        s1[n] = __builtin_amdgcn_mfma_f32_16x16x32_bf16(kf[n][kk], qf[1][kk],
                                                        s1[n], 0, 0, 0);
    __builtin_amdgcn_s_setprio(0);
    float ls1 = 0.f;
    uint2 pw1[4];
#pragma unroll
    for (int n = 0; n < 4; ++n) {
      const float p0 = vexp2(s1[n][0]);
      const float p1 = vexp2(s1[n][1]);
      const float p2 = vexp2(s1[n][2]);
      const float p3 = vexp2(s1[n][3]);
      ls1 += (p0 + p1) + (p2 + p3);
      pw1[n].x = cvtpk(p0, p1); pw1[n].y = cvtpk(p2, p3);
    }
    lrow[1] += ls1;

    bf16x8 pf0[2], pf1[2];
#pragma unroll
    for (int kk = 0; kk < 2; ++kk)
      pf0[kk] = *(const bf16x8*)&lPw[lr * 64 + (((kk * 4 + lk) ^ m7) << 3)];
#pragma unroll
    for (int n = 0; n < 4; ++n)
      *(uint2*)&lPw[lr * 64 + (((2 * n + lkh) ^ m7) << 3) + lkb * 4] = pw1[n];
#pragma unroll
    for (int kk = 0; kk < 2; ++kk)
      pf1[kk] = *(const bf16x8*)&lPw[lr * 64 + (((kk * 4 + lk) ^ m7) << 3)];

    __builtin_amdgcn_s_setprio(1);
#pragma unroll
    for (int n = 0; n < 4; ++n)
#pragma unroll
      for (int kk = 0; kk < 2; ++kk) {
        const int ub = (kk * 4 + lk) ^ m7;
        bf16x8 vf = *(const bf16x8*)&bufV[(n * 16 + lr) * 64 + ub * 8];
        oacc[0][n] = __builtin_amdgcn_mfma_f32_16x16x32_bf16(pf0[kk], vf,
                                                             oacc[0][n], 0, 0, 0);
        oacc[1][n] = __builtin_amdgcn_mfma_f32_16x16x32_bf16(pf1[kk], vf,
                                                             oacc[1][n], 0, 0, 0);
      }
    __builtin_amdgcn_s_setprio(0);

    __syncthreads();
  }
#undef ASTAGE

  float rinv[2][4];
#pragma unroll
  for (int m = 0; m < 2; ++m) {
    float s = lrow[m];
    s += __shfl_xor(s, 16);
    s += __shfl_xor(s, 32);
#pragma unroll
    for (int r = 0; r < 4; ++r) rinv[m][r] = 1.0f / __shfl(s, lk * 4 + r);
  }

  const int b = bh >> 4, h = bh & 15;
#pragma unroll
  for (int m = 0; m < 2; ++m)
#pragma unroll
    for (int n = 0; n < 4; ++n)
#pragma unroll
      for (int r = 0; r < 4; ++r) {
        const int qrow = q0 + w * 32 + m * 16 + lk * 4 + r;
        const int grow = b * kSQ + qrow;
        const int p = grow >> 8, rA = grow & 255;
        const int u = (n * 2 + (lr >> 3)) ^ (rA & 7);
        Obf[(((size_t)p * 16 + h) * 256 + rA) * 64 + u * 8 + (lr & 7)] =
            f2bf(oacc[m][n][r] * rinv[m][r]);
      }
}

// ---------------------------------------------------------------------------
// Kernel 6: t_o = O(bf16, swizzled-tiled) @ out_lora_down
__global__ __launch_bounds__(256) void k_tdown(const unsigned short* __restrict__ Ob,
                                               const float* __restrict__ dn,
                                               float* __restrict__ t_o) {
  const int row = blockIdx.x;
  const int tid = threadIdx.x;
  const int p = row >> 8, r = row & 255;
  const int kt = tid >> 4, us = (tid >> 1) & 7, e = (tid & 1) * 4;
  const int u = us ^ (r & 7);
  short4 v4 = *reinterpret_cast<const short4*>(
      &Ob[(((size_t)p * 16 + kt) * 256 + r) * 64 + u * 8 + e]);
  short vs[4] = {v4.x, v4.y, v4.z, v4.w};
  float a[4] = {0.f, 0.f, 0.f, 0.f};
#pragma unroll
  for (int e2 = 0; e2 < 4; ++e2) {
    const float x = bf2f((unsigned short)vs[e2]);
    const float* dr = dn + (size_t)(tid * 4 + e2) * 4;
    a[0] += x * dr[0]; a[1] += x * dr[1]; a[2] += x * dr[2]; a[3] += x * dr[3];
  }
  __shared__ float red[4][4];
  const int l = tid & 63, w = tid >> 6;
#pragma unroll
  for (int k2 = 0; k2 < 4; ++k2) {
    float v = a[k2];
#pragma unroll
    for (int m = 1; m < 64; m <<= 1) v += __shfl_xor(v, m);
    if (l == 0) red[w][k2] = v;
  }
  __syncthreads();
  if (tid < 4)
    t_o[(size_t)row * 4 + tid] = red[0][tid] + red[1][tid] + red[2][tid] + red[3][tid];
}

// ---------------------------------------------------------------------------
extern "C" void kernel_launch(void* const* d_in, const int* in_sizes, int n_in,
                              void* d_out, int out_size, void* d_ws, size_t ws_size,
                              hipStream_t stream) {
  (void)in_sizes; (void)n_in; (void)out_size; (void)ws_size;
  const float* hs   = (const float*)d_in[0];
  const float* enc  = (const float*)d_in[1];
  const float* Wq   = (const float*)d_in[2];
  const float* Wk   = (const float*)d_in[3];
  const float* Wv   = (const float*)d_in[4];
  const float* Wo   = (const float*)d_in[5];
  const float* bo   = (const float*)d_in[6];
  const float* q_dn = (const float*)d_in[7];
  const float* q_up = (const float*)d_in[8];
  const float* k_dn = (const float*)d_in[9];
  const float* k_up = (const float*)d_in[10];
  const float* v_dn = (const float*)d_in[11];
  const float* v_up = (const float*)d_in[12];
  const float* o_dn = (const float*)d_in[13];
  const float* o_up = (const float*)d_in[14];

  char* ws = (char*)d_ws;
  size_t off = 0;
  auto alloc = [&](size_t bytes) -> void* {
    void* p = ws + off;
    off += (bytes + 255) & ~(size_t)255;
    return p;
  };
  const size_t ACT = (size_t)kM * kD * 2;
  unsigned short* hsb  = (unsigned short*)alloc(ACT);
  unsigned short* encb = (unsigned short*)alloc(ACT);
  unsigned short* Wqt  = (unsigned short*)alloc((size_t)1024 * 1024 * 2);
  unsigned short* Wkvt = (unsigned short*)alloc((size_t)2048 * 1024 * 2);
  unsigned short* Wot  = (unsigned short*)alloc((size_t)1024 * 1024 * 2);
  unsigned short* Qhp  = (unsigned short*)alloc(ACT);
  unsigned short* Khp  = (unsigned short*)alloc(ACT);
  unsigned short* Vhp  = (unsigned short*)alloc(ACT);
  float* tq  = (float*)alloc((size_t)kM * 4 * 4);
  float* tkv = (float*)alloc((size_t)kM * 8 * 4);
  float* to  = (float*)alloc((size_t)kM * 4 * 4);
  unsigned short* Vtt = hsb;   // alias: V^T reuses hidden bf16 buffer
  unsigned short* Ob  = encb;  // alias: attention O reuses encoder bf16 buffer

  k_prep_wt<<<dim3(2 * kM + 1024), dim3(256), 0, stream>>>(
      hs, enc, q_dn, k_dn, v_dn, Wq, Wk, Wv, Wo,
      hsb, encb, tq, tkv, Wqt, Wkvt, Wot);

  k_gemm_qkv<<<dim3(384), dim3(512), 0, stream>>>(
      hsb, encb, Wqt, Wkvt, tq, tkv, q_up, k_up, v_up, Qhp, Khp, Vhp);

  k_vt<<<dim3(32, 64), dim3(256), 0, stream>>>(Vhp, Vtt);
  k_attn<<<dim3(16, 64), dim3(256), 0, stream>>>(Qhp, Khp, Vtt, Ob);
  k_tdown<<<dim3(kM), dim3(256), 0, stream>>>(Ob, o_dn, to);

  k_gemm_out<<<dim3(128), dim3(512), 0, stream>>>(Ob, Wot, to, o_up, bo,
                                                  (float*)d_out);
}

// Round 8
// 362.797 us; speedup vs baseline: 1.3787x; 1.3787x over previous
//
#include <hip/hip_runtime.h>
#include <hip/hip_bf16.h>

typedef __attribute__((ext_vector_type(8))) short bf16x8;
typedef __attribute__((ext_vector_type(4))) float f32x4;

#define DEVFN static __device__ __forceinline__

constexpr int kSQ = 2048, kSKV = 2048, kD = 1024, kH = 16;
constexpr int kM = 4 * kSQ;   // 8192 rows (B*SQ)

DEVFN unsigned short f2bf(float f) {
  union { float f; unsigned u; } v; v.f = f;
  unsigned r = v.u + 0x7FFFu + ((v.u >> 16) & 1u);
  return (unsigned short)(r >> 16);
}
DEVFN float bf2f(unsigned short h) {
  union { unsigned u; float f; } v; v.u = ((unsigned)h) << 16; return v.f;
}
DEVFN unsigned cvtpk(float lo, float hi) {
  unsigned r;
  asm("v_cvt_pk_bf16_f32 %0, %1, %2" : "=v"(r) : "v"(lo), "v"(hi));
  return r;
}
DEVFN float vexp2(float x) {
  float r;
  asm("v_exp_f32 %0, %1" : "=v"(r) : "v"(x));
  return r;
}

DEVFN void gload16(const void* g, void* l) {
  __builtin_amdgcn_global_load_lds(
      (const __attribute__((address_space(1))) unsigned int*)g,
      (__attribute__((address_space(3))) unsigned int*)l, 16, 0, 0);
}

// ---------------------------------------------------------------------------
// Swizzled-tiled operand layouts (producer-side swizzle -> GEMM staging is
// perfectly LINEAR global_load_lds; ds_read_b128 frag reads are conflict-free):
//   A (8192x1024):  [p<32][kt<16][r<256][u<8][8]   u = (c>>3) ^ (r&7)
//   B (N-major):    [np<N/128][kt<16][r<128][u<8][8]  same rule
// ---------------------------------------------------------------------------

// Kernel 1 (merged): blocks [0, 2*kM): activation fp32->bf16 (swizzled-tiled)
// + LoRA-down dots. blocks [2*kM, 2*kM+1024): weight convert+transpose.
__global__ __launch_bounds__(256) void k_prep_wt(
    const float* __restrict__ hs, const float* __restrict__ enc,
    const float* __restrict__ qdn, const float* __restrict__ kdn,
    const float* __restrict__ vdn,
    const float* __restrict__ Wq, const float* __restrict__ Wk,
    const float* __restrict__ Wv, const float* __restrict__ Wo,
    unsigned short* __restrict__ hsb, unsigned short* __restrict__ encb,
    float* __restrict__ tq, float* __restrict__ tkv,
    unsigned short* __restrict__ Wqt, unsigned short* __restrict__ Wkvt,
    unsigned short* __restrict__ Wot) {
  __shared__ float red[4][8];
  __shared__ unsigned short tile[64][65];
  const int bid = blockIdx.x;
  const int tid = threadIdx.x;

  if (bid < 2 * kM) {
    const bool isH = bid < kM;
    const int rr = isH ? bid : bid - kM;
    const float* srcRow = (isH ? hs : enc) + (size_t)rr * kD;
    unsigned short* dstB = isH ? hsb : encb;

    float4 x = reinterpret_cast<const float4*>(srcRow)[tid];
    short4 o;
    o.x = (short)f2bf(x.x); o.y = (short)f2bf(x.y);
    o.z = (short)f2bf(x.z); o.w = (short)f2bf(x.w);
    {
      const int p = rr >> 8, r = rr & 255;
      const int kt = tid >> 4, us = (tid >> 1) & 7, e = (tid & 1) * 4;
      const int u = us ^ (r & 7);
      *reinterpret_cast<short4*>(
          &dstB[(((size_t)(p * 16 + kt)) * 256 + r) * 64 + u * 8 + e]) = o;
    }

    float xs[4] = {x.x, x.y, x.z, x.w};
    float a[4] = {0.f, 0.f, 0.f, 0.f};
    float bacc[4] = {0.f, 0.f, 0.f, 0.f};
    const float* dnA = isH ? qdn : kdn;
    const int base = tid * 4;
#pragma unroll
    for (int e = 0; e < 4; ++e) {
      const float* dr = dnA + (size_t)(base + e) * 4;
      a[0] += xs[e] * dr[0]; a[1] += xs[e] * dr[1];
      a[2] += xs[e] * dr[2]; a[3] += xs[e] * dr[3];
    }
    if (!isH) {
#pragma unroll
      for (int e = 0; e < 4; ++e) {
        const float* dr = vdn + (size_t)(base + e) * 4;
        bacc[0] += xs[e] * dr[0]; bacc[1] += xs[e] * dr[1];
        bacc[2] += xs[e] * dr[2]; bacc[3] += xs[e] * dr[3];
      }
    }
    const int l = tid & 63, w = tid >> 6;
    float vals[8] = {a[0], a[1], a[2], a[3], bacc[0], bacc[1], bacc[2], bacc[3]};
#pragma unroll
    for (int k2 = 0; k2 < 8; ++k2) {
      float v = vals[k2];
#pragma unroll
      for (int m = 1; m < 64; m <<= 1) v += __shfl_xor(v, m);
      if (l == 0) red[w][k2] = v;
    }
    __syncthreads();
    if (tid < 8) {
      float s = red[0][tid] + red[1][tid] + red[2][tid] + red[3][tid];
      if (isH) {
        if (tid < 4) tq[(size_t)rr * 4 + tid] = s;
      } else {
        tkv[(size_t)rr * 8 + tid] = s;   // 0..3 = k-down, 4..7 = v-down
      }
    }
  } else {
    const int t2 = bid - 2 * kM;
    const int wid = t2 >> 8, tt = t2 & 255;
    const float* W = (wid == 0) ? Wq : (wid == 1) ? Wk : (wid == 2) ? Wv : Wo;
    unsigned short* Wt = (wid == 0) ? Wqt : (wid <= 2) ? Wkvt : Wot;
    const int npOff = (wid == 2) ? 8 : 0;   // V weights occupy panels 8..15
    const int tk0 = (tt & 15) * 64;
    const int tn0 = (tt >> 4) * 64;
    for (int i = tid; i < 4096; i += 256) {
      int r = i >> 6, c = i & 63;
      tile[r][c] = f2bf(W[(size_t)(tk0 + r) * 1024 + tn0 + c]);
    }
    __syncthreads();
    const int kt = tk0 >> 6;
    for (int i = tid; i < 4096; i += 256) {
      int r2 = i >> 6, c2 = i & 63;       // r2 = n-offset, c2 = k-offset
      const int n = tn0 + r2;
      const int np = (n >> 7) + npOff, rB = n & 127;
      const int u = (c2 >> 3) ^ (rB & 7), e = c2 & 7;
      Wt[(((size_t)np * 16 + kt) * 128 + rB) * 64 + u * 8 + e] = tile[c2][r2];
    }
  }
}

// ---------------------------------------------------------------------------
// Wave-autonomous GEMM core: each WAVE owns a 64x128 output tile with a
// private 24KB LDS buffer (A 8KB + B 16KB). No barriers, no cross-wave sync.
// Per K-step: vmcnt(0) [own loads from previous step already landed] ->
// ds_read all frags -> lgkmcnt(0)+sched_barrier (buffer reuse fence) ->
// restage same buffer with next tile -> MFMA from registers.

#define WSTAGE(kt) do {                                                       \
    _Pragma("unroll") for (int j = 0; j < 8; ++j)                             \
      gload16(Ag0 + (size_t)(kt) * 16384 + j * 512 + l * 8, &lbA[j * 512]);   \
    _Pragma("unroll") for (int j = 0; j < 16; ++j)                            \
      gload16(Bg0 + (size_t)(kt) * 8192 + j * 512 + l * 8, &lbB[j * 512]);    \
  } while (0)

#define WGEMM_LOOP()                                                          \
  WSTAGE(0);                                                                  \
  for (int kt = 0; kt < 16; ++kt) {                                           \
    asm volatile("s_waitcnt vmcnt(0)" ::: "memory");                          \
    __builtin_amdgcn_sched_barrier(0);                                        \
    bf16x8 af[4][2], bfr[8];                                                  \
    _Pragma("unroll")                                                         \
    for (int m = 0; m < 4; ++m)                                               \
      _Pragma("unroll")                                                       \
      for (int kk = 0; kk < 2; ++kk)                                          \
        af[m][kk] = *(const bf16x8*)&lbA[(m * 16 + lr) * 64 +                 \
                     (((kk * 4 + lk) ^ (lr & 7)) << 3)];                      \
    _Pragma("unroll")                                                         \
    for (int n = 0; n < 8; ++n)                                               \
      bfr[n] = *(const bf16x8*)&lbB[(n * 16 + lr) * 64 +                      \
                (((lk) ^ (lr & 7)) << 3)];                                    \
    __builtin_amdgcn_s_setprio(1);                                            \
    _Pragma("unroll")                                                         \
    for (int m = 0; m < 4; ++m)                                               \
      _Pragma("unroll")                                                       \
      for (int n = 0; n < 8; ++n)                                             \
        acc[m][n] = __builtin_amdgcn_mfma_f32_16x16x32_bf16(                  \
            af[m][0], bfr[n], acc[m][n], 0, 0, 0);                            \
    __builtin_amdgcn_s_setprio(0);                                            \
    _Pragma("unroll")                                                         \
    for (int n = 0; n < 8; ++n)                                               \
      bfr[n] = *(const bf16x8*)&lbB[(n * 16 + lr) * 64 +                      \
                (((4 + lk) ^ (lr & 7)) << 3)];                                \
    asm volatile("s_waitcnt lgkmcnt(0)" ::: "memory");                        \
    __builtin_amdgcn_sched_barrier(0);                                        \
    if (kt < 15) WSTAGE(kt + 1);                                              \
    __builtin_amdgcn_s_setprio(1);                                            \
    _Pragma("unroll")                                                         \
    for (int m = 0; m < 4; ++m)                                               \
      _Pragma("unroll")                                                       \
      for (int n = 0; n < 8; ++n)                                             \
        acc[m][n] = __builtin_amdgcn_mfma_f32_16x16x32_bf16(                  \
            af[m][1], bfr[n], acc[m][n], 0, 0, 0);                            \
    __builtin_amdgcn_s_setprio(0);                                            \
  }

// Kernel 2: QKV projection. 1536 blocks x 128 thr (2 wave-tiles each).
// Wave-tiles: [0,1024): Q (128 ms x 8 nt); [1024,3072): K|V (128 ms x 16 nt).
__global__ __launch_bounds__(128, 2) void k_gemm_qkv(
    const unsigned short* __restrict__ hsb, const unsigned short* __restrict__ encb,
    const unsigned short* __restrict__ Wqt, const unsigned short* __restrict__ Wkvt,
    const float* __restrict__ tq, const float* __restrict__ tkv,
    const float* __restrict__ q_up, const float* __restrict__ k_up,
    const float* __restrict__ v_up,
    unsigned short* __restrict__ Qhp, unsigned short* __restrict__ Khp,
    unsigned short* __restrict__ Vhp) {
  __shared__ unsigned short lds[2][12288];
  const int tid = threadIdx.x;
  const int l = tid & 63, w = tid >> 6;
  const int rid = ((int)blockIdx.x & 7) * 192 + ((int)blockIdx.x >> 3);
  const int t = rid * 2 + w;

  const unsigned short *Ag, *Bg;
  const float *tmat, *up;
  unsigned short* dst;
  int ms, colbase, tstr;
  if (t < 1024) {
    ms = t >> 3;
    const int nt = t & 7;
    Ag = hsb; Bg = Wqt + (size_t)nt * 16 * 8192;
    tmat = tq; tstr = 4; up = q_up; dst = Qhp; colbase = nt * 128;
  } else {
    const int t2 = t - 1024;
    ms = t2 >> 4;
    const int nt = t2 & 15;
    Ag = encb; Bg = Wkvt + (size_t)nt * 16 * 8192;
    if (nt < 8) { tmat = tkv;     up = k_up; dst = Khp; }
    else        { tmat = tkv + 4; up = v_up; dst = Vhp; }
    tstr = 8; colbase = (nt & 7) * 128;
  }
  const int p = ms >> 2, r0 = (ms & 3) * 64;
  const unsigned short* Ag0 = Ag + ((size_t)p * 16) * 16384 + r0 * 64;
  const unsigned short* Bg0 = Bg;
  unsigned short* lbA = &lds[w][0];
  unsigned short* lbB = &lds[w][4096];
  const int lr = l & 15, lk = l >> 4;

  f32x4 acc[4][8];
  const f32x4 zero = {0.f, 0.f, 0.f, 0.f};
#pragma unroll
  for (int m = 0; m < 4; ++m)
#pragma unroll
    for (int n = 0; n < 8; ++n) acc[m][n] = zero;

  WGEMM_LOOP()

#pragma unroll
  for (int n = 0; n < 8; ++n) {
    const int gcol = colbase + n * 16 + lr;
    const float u0 = up[gcol], u1 = up[1024 + gcol];
    const float u2 = up[2048 + gcol], u3 = up[3072 + gcol];
    const int h = gcol >> 6, d = gcol & 63;
#pragma unroll
    for (int m = 0; m < 4; ++m) {
#pragma unroll
      for (int r = 0; r < 4; ++r) {
        const int grow = ms * 64 + m * 16 + lk * 4 + r;
        const float4 tt = *reinterpret_cast<const float4*>(tmat + (size_t)grow * tstr);
        const float val = acc[m][n][r] + tt.x * u0 + tt.y * u1 + tt.z * u2 + tt.w * u3;
        const int b = grow >> 11, s = grow & 2047;
        dst[(((size_t)(b * kH + h)) * 2048 + s) * 64 + d] = f2bf(val);
      }
    }
  }
}

// Kernel 3: out = Ob @ Wot^T + bias + t_o @ o_up (f32). 512 blocks x 128 thr.
__global__ __launch_bounds__(128, 2) void k_gemm_out(
    const unsigned short* __restrict__ Ob, const unsigned short* __restrict__ Wot,
    const float* __restrict__ tmat, const float* __restrict__ up,
    const float* __restrict__ bias, float* __restrict__ outp) {
  __shared__ unsigned short lds[2][12288];
  const int tid = threadIdx.x;
  const int l = tid & 63, w = tid >> 6;
  const int rid = ((int)blockIdx.x & 7) * 64 + ((int)blockIdx.x >> 3);
  const int t = rid * 2 + w;
  const int ms = t >> 3, nt = t & 7;
  const unsigned short* Ag0 = Ob + ((size_t)(ms >> 2) * 16) * 16384 + (ms & 3) * 64 * 64;
  const unsigned short* Bg0 = Wot + (size_t)nt * 16 * 8192;
  unsigned short* lbA = &lds[w][0];
  unsigned short* lbB = &lds[w][4096];
  const int lr = l & 15, lk = l >> 4;

  f32x4 acc[4][8];
  const f32x4 zero = {0.f, 0.f, 0.f, 0.f};
#pragma unroll
  for (int m = 0; m < 4; ++m)
#pragma unroll
    for (int n = 0; n < 8; ++n) acc[m][n] = zero;

  WGEMM_LOOP()

#pragma unroll
  for (int n = 0; n < 8; ++n) {
    const int gcol = nt * 128 + n * 16 + lr;
    const float u0 = up[gcol], u1 = up[1024 + gcol];
    const float u2 = up[2048 + gcol], u3 = up[3072 + gcol];
    const float bz = bias[gcol];
#pragma unroll
    for (int m = 0; m < 4; ++m) {
#pragma unroll
      for (int r = 0; r < 4; ++r) {
        const int grow = ms * 64 + m * 16 + lk * 4 + r;
        const float4 tt = *reinterpret_cast<const float4*>(tmat + (size_t)grow * 4);
        outp[(size_t)grow * 1024 + gcol] =
            acc[m][n][r] + tt.x * u0 + tt.y * u1 + tt.z * u2 + tt.w * u3 + bz;
      }
    }
  }
}

// ---------------------------------------------------------------------------
// Kernel 4: V head-layout transpose: (bh, s, d) -> (bh, d, s)
__global__ __launch_bounds__(256) void k_vt(const unsigned short* __restrict__ Vh,
                                            unsigned short* __restrict__ Vt) {
  __shared__ unsigned short tile[64][65];
  const int bh = blockIdx.y;
  const int s0 = blockIdx.x * 64;
  const unsigned short* src = Vh + ((size_t)bh * kSKV + s0) * 64;
  for (int i = threadIdx.x; i < 4096; i += 256) {
    int r = i >> 6, c = i & 63;
    tile[r][c] = src[(size_t)r * 64 + c];
  }
  __syncthreads();
  unsigned short* dst = Vt + (size_t)bh * 64 * kSKV + s0;
  for (int i = threadIdx.x; i < 4096; i += 256) {
    int r = i >> 6, c = i & 63;
    dst[(size_t)r * kSKV + c] = tile[c][r];
  }
}

// ---------------------------------------------------------------------------
// Kernel 5: flash attention (round-3 structure, best measured). Output written
// in swizzled-tiled A layout for the out-GEMM.
__global__ __launch_bounds__(256) void k_attn(
    const unsigned short* __restrict__ Qh, const unsigned short* __restrict__ Kh,
    const unsigned short* __restrict__ Vt, unsigned short* __restrict__ Obf) {
  __shared__ unsigned short lK[2][4096];
  __shared__ unsigned short lV[2][4096];
  __shared__ __align__(16) unsigned short lP[4][1024];

  const int bid = blockIdx.x + 16 * blockIdx.y;              // 1024 blocks
  const int rid = (bid & 7) * 128 + (bid >> 3);
  const int q0 = (rid & 15) * 128;
  const int bh = rid >> 4;

  const int tid = threadIdx.x;
  const int l = tid & 63, w = tid >> 6;
  const int lr = l & 15, lk = l >> 4;
  const int m7 = lr & 7;
  const int lkh = lk >> 1, lkb = lk & 1;

  const unsigned short* Qb = Qh + (size_t)bh * kSQ * 64;
  const unsigned short* Kb = Kh + (size_t)bh * kSKV * 64;
  const unsigned short* Vb = Vt + (size_t)bh * 64 * kSKV;

  const float QS = 0.125f * 1.4426950408889634f;
  bf16x8 qf[2][2];
#pragma unroll
  for (int m = 0; m < 2; ++m)
#pragma unroll
    for (int kk = 0; kk < 2; ++kk) {
      bf16x8 v = *(const bf16x8*)
          &Qb[(size_t)(q0 + w * 32 + m * 16 + lr) * 64 + kk * 32 + lk * 8];
#pragma unroll
      for (int j = 0; j < 8; ++j) {
        unsigned short u = (unsigned short)v[j];
        v[j] = (short)f2bf(bf2f(u) * QS);
      }
      qf[m][kk] = v;
    }

  f32x4 oacc[2][4];
  const f32x4 zero = {0.f, 0.f, 0.f, 0.f};
#pragma unroll
  for (int m = 0; m < 2; ++m)
#pragma unroll
    for (int n = 0; n < 4; ++n) oacc[m][n] = zero;
  float lrow[2] = {0.f, 0.f};

  const int sr8 = l >> 3;
  const int su = (l & 7) ^ sr8;
  unsigned short* lPw = lP[w];

#define ASTAGE(dbuf, tile) do { \
    _Pragma("unroll") for (int cc = 0; cc < 2; ++cc) { \
      const int c = 2 * w + cc; const int row = c * 8 + sr8; \
      gload16(Kb + (size_t)((tile) * 64 + row) * 64 + su * 8, &lK[dbuf][c * 512]); \
      gload16(Vb + (size_t)row * kSKV + (tile) * 64 + su * 8, &lV[dbuf][c * 512]); \
    } } while (0)

  ASTAGE(0, 0);
  __syncthreads();

#pragma unroll 2
  for (int kt = 0; kt < 32; ++kt) {
    const int cur = kt & 1;
    if (kt < 31) ASTAGE(cur ^ 1, kt + 1);
    const unsigned short* bufK = lK[cur];
    const unsigned short* bufV = lV[cur];

    bf16x8 kf[4][2];
#pragma unroll
    for (int n = 0; n < 4; ++n)
#pragma unroll
      for (int kk = 0; kk < 2; ++kk) {
        const int ub = (kk * 4 + lk) ^ m7;
        kf[n][kk] = *(const bf16x8*)&bufK[(n * 16 + lr) * 64 + ub * 8];
      }

    f32x4 s0[4];
#pragma unroll
    for (int n = 0; n < 4; ++n) s0[n] = zero;
    __builtin_amdgcn_s_setprio(1);
#pragma unroll
    for (int kk = 0; kk < 2; ++kk)
#pragma unroll
      for (int n = 0; n < 4; ++n)
        s0[n] = __builtin_amdgcn_mfma_f32_16x16x32_bf16(kf[n][kk], qf[0][kk],
                                                        s0[n], 0, 0, 0);
    __builtin_amdgcn_s_setprio(0);
    float ls0 = 0.f;
#pragma unroll
    for (int n = 0; n < 4; ++n) {
      const float p0 = vexp2(s0[n][0]);
      const float p1 = vexp2(s0[n][1]);
      const float p2 = vexp2(s0[n][2]);
      const float p3 = vexp2(s0[n][3]);
      ls0 += (p0 + p1) + (p2 + p3);
      uint2 pv; pv.x = cvtpk(p0, p1); pv.y = cvtpk(p2, p3);
      *(uint2*)&lPw[lr * 64 + (((2 * n + lkh) ^ m7) << 3) + lkb * 4] = pv;
    }
    lrow[0] += ls0;

    f32x4 s1[4];
#pragma unroll
    for (int n = 0; n < 4; ++n) s1[n] = zero;
    __builtin_amdgcn_s_setprio(1);
#pragma unroll
    for (int kk = 0; kk < 2; ++kk)
#pragma unroll
      for (int n = 0; n < 4; ++n)
        s1[n] = __builtin_amdgcn_mfma_f32_16x16x32_bf16(kf[n][kk], qf[1][kk],
                                                        s1[n], 0, 0, 0);
    __builtin_amdgcn_s_setprio(0);
    float ls1 = 0.f;
    uint2 pw1[4];
#pragma unroll
    for (int n = 0; n < 4; ++n) {
      const float p0 = vexp2(s1[n][0]);
      const float p1 = vexp2(s1[n][1]);
      const float p2 = vexp2(s1[n][2]);
      const float p3 = vexp2(s1[n][3]);
      ls1 += (p0 + p1) + (p2 + p3);
      pw1[n].x = cvtpk(p0, p1); pw1[n].y = cvtpk(p2, p3);
    }
    lrow[1] += ls1;

    bf16x8 pf0[2], pf1[2];
#pragma unroll
    for (int kk = 0; kk < 2; ++kk)
      pf0[kk] = *(const bf16x8*)&lPw[lr * 64 + (((kk * 4 + lk) ^ m7) << 3)];
#pragma unroll
    for (int n = 0; n < 4; ++n)
      *(uint2*)&lPw[lr * 64 + (((2 * n + lkh) ^ m7) << 3) + lkb * 4] = pw1[n];
#pragma unroll
    for (int kk = 0; kk < 2; ++kk)
      pf1[kk] = *(const bf16x8*)&lPw[lr * 64 + (((kk * 4 + lk) ^ m7) << 3)];

    __builtin_amdgcn_s_setprio(1);
#pragma unroll
    for (int n = 0; n < 4; ++n)
#pragma unroll
      for (int kk = 0; kk < 2; ++kk) {
        const int ub = (kk * 4 + lk) ^ m7;
        bf16x8 vf = *(const bf16x8*)&bufV[(n * 16 + lr) * 64 + ub * 8];
        oacc[0][n] = __builtin_amdgcn_mfma_f32_16x16x32_bf16(pf0[kk], vf,
                                                             oacc[0][n], 0, 0, 0);
        oacc[1][n] = __builtin_amdgcn_mfma_f32_16x16x32_bf16(pf1[kk], vf,
                                                             oacc[1][n], 0, 0, 0);
      }
    __builtin_amdgcn_s_setprio(0);

    __syncthreads();
  }
#undef ASTAGE

  float rinv[2][4];
#pragma unroll
  for (int m = 0; m < 2; ++m) {
    float s = lrow[m];
    s += __shfl_xor(s, 16);
    s += __shfl_xor(s, 32);
#pragma unroll
    for (int r = 0; r < 4; ++r) rinv[m][r] = 1.0f / __shfl(s, lk * 4 + r);
  }

  const int b = bh >> 4, h = bh & 15;
#pragma unroll
  for (int m = 0; m < 2; ++m)
#pragma unroll
    for (int n = 0; n < 4; ++n)
#pragma unroll
      for (int r = 0; r < 4; ++r) {
        const int qrow = q0 + w * 32 + m * 16 + lk * 4 + r;
        const int grow = b * kSQ + qrow;
        const int p = grow >> 8, rA = grow & 255;
        const int u = (n * 2 + (lr >> 3)) ^ (rA & 7);
        Obf[(((size_t)p * 16 + h) * 256 + rA) * 64 + u * 8 + (lr & 7)] =
            f2bf(oacc[m][n][r] * rinv[m][r]);
      }
}

// ---------------------------------------------------------------------------
// Kernel 6: t_o = O(bf16, swizzled-tiled) @ out_lora_down
__global__ __launch_bounds__(256) void k_tdown(const unsigned short* __restrict__ Ob,
                                               const float* __restrict__ dn,
                                               float* __restrict__ t_o) {
  const int row = blockIdx.x;
  const int tid = threadIdx.x;
  const int p = row >> 8, r = row & 255;
  const int kt = tid >> 4, us = (tid >> 1) & 7, e = (tid & 1) * 4;
  const int u = us ^ (r & 7);
  short4 v4 = *reinterpret_cast<const short4*>(
      &Ob[(((size_t)p * 16 + kt) * 256 + r) * 64 + u * 8 + e]);
  short vs[4] = {v4.x, v4.y, v4.z, v4.w};
  float a[4] = {0.f, 0.f, 0.f, 0.f};
#pragma unroll
  for (int e2 = 0; e2 < 4; ++e2) {
    const float x = bf2f((unsigned short)vs[e2]);
    const float* dr = dn + (size_t)(tid * 4 + e2) * 4;
    a[0] += x * dr[0]; a[1] += x * dr[1]; a[2] += x * dr[2]; a[3] += x * dr[3];
  }
  __shared__ float red[4][4];
  const int l = tid & 63, w = tid >> 6;
#pragma unroll
  for (int k2 = 0; k2 < 4; ++k2) {
    float v = a[k2];
#pragma unroll
    for (int m = 1; m < 64; m <<= 1) v += __shfl_xor(v, m);
    if (l == 0) red[w][k2] = v;
  }
  __syncthreads();
  if (tid < 4)
    t_o[(size_t)row * 4 + tid] = red[0][tid] + red[1][tid] + red[2][tid] + red[3][tid];
}

// ---------------------------------------------------------------------------
extern "C" void kernel_launch(void* const* d_in, const int* in_sizes, int n_in,
                              void* d_out, int out_size, void* d_ws, size_t ws_size,
                              hipStream_t stream) {
  (void)in_sizes; (void)n_in; (void)out_size; (void)ws_size;
  const float* hs   = (const float*)d_in[0];
  const float* enc  = (const float*)d_in[1];
  const float* Wq   = (const float*)d_in[2];
  const float* Wk   = (const float*)d_in[3];
  const float* Wv   = (const float*)d_in[4];
  const float* Wo   = (const float*)d_in[5];
  const float* bo   = (const float*)d_in[6];
  const float* q_dn = (const float*)d_in[7];
  const float* q_up = (const float*)d_in[8];
  const float* k_dn = (const float*)d_in[9];
  const float* k_up = (const float*)d_in[10];
  const float* v_dn = (const float*)d_in[11];
  const float* v_up = (const float*)d_in[12];
  const float* o_dn = (const float*)d_in[13];
  const float* o_up = (const float*)d_in[14];

  char* ws = (char*)d_ws;
  size_t off = 0;
  auto alloc = [&](size_t bytes) -> void* {
    void* p = ws + off;
    off += (bytes + 255) & ~(size_t)255;
    return p;
  };
  const size_t ACT = (size_t)kM * kD * 2;
  unsigned short* hsb  = (unsigned short*)alloc(ACT);
  unsigned short* encb = (unsigned short*)alloc(ACT);
  unsigned short* Wqt  = (unsigned short*)alloc((size_t)1024 * 1024 * 2);
  unsigned short* Wkvt = (unsigned short*)alloc((size_t)2048 * 1024 * 2);
  unsigned short* Wot  = (unsigned short*)alloc((size_t)1024 * 1024 * 2);
  unsigned short* Qhp  = (unsigned short*)alloc(ACT);
  unsigned short* Khp  = (unsigned short*)alloc(ACT);
  unsigned short* Vhp  = (unsigned short*)alloc(ACT);
  float* tq  = (float*)alloc((size_t)kM * 4 * 4);
  float* tkv = (float*)alloc((size_t)kM * 8 * 4);
  float* to  = (float*)alloc((size_t)kM * 4 * 4);
  unsigned short* Vtt = hsb;   // alias: V^T reuses hidden bf16 buffer
  unsigned short* Ob  = encb;  // alias: attention O reuses encoder bf16 buffer

  k_prep_wt<<<dim3(2 * kM + 1024), dim3(256), 0, stream>>>(
      hs, enc, q_dn, k_dn, v_dn, Wq, Wk, Wv, Wo,
      hsb, encb, tq, tkv, Wqt, Wkvt, Wot);

  k_gemm_qkv<<<dim3(1536), dim3(128), 0, stream>>>(
      hsb, encb, Wqt, Wkvt, tq, tkv, q_up, k_up, v_up, Qhp, Khp, Vhp);

  k_vt<<<dim3(32, 64), dim3(256), 0, stream>>>(Vhp, Vtt);
  k_attn<<<dim3(16, 64), dim3(256), 0, stream>>>(Qhp, Khp, Vtt, Ob);
  k_tdown<<<dim3(kM), dim3(256), 0, stream>>>(Ob, o_dn, to);

  k_gemm_out<<<dim3(512), dim3(128), 0, stream>>>(Ob, Wot, to, o_up, bo,
                                                  (float*)d_out);
}